// Round 1
// baseline (148.214 us; speedup 1.0000x reference)
//
#include <hip/hip_runtime.h>

#define NB 8
#define NT 2048
#define ND 512
#define NH 128
#define NF 512
#define NKW 7
#define NTOK (NB*NT)   // 16384
#define KP 960         // padded K' = 7*128 + 64 (bias + zero pad)

typedef float f32x4 __attribute__((ext_vector_type(4)));
typedef __bf16 bf16x8 __attribute__((ext_vector_type(8)));
typedef unsigned short u16;
typedef unsigned int u32;
typedef u16 u16x8 __attribute__((ext_vector_type(8)));

__device__ __forceinline__ u16 f2bf(float f){
  u32 u = __builtin_bit_cast(u32, f);
  return (u16)((u + 0x7fffu + ((u>>16)&1u)) >> 16);
}
__device__ __forceinline__ float bf2f(u16 s){
  u32 u = ((u32)s)<<16;
  return __builtin_bit_cast(float, u);
}
__device__ __forceinline__ void gload_lds16(const void* g, void* l){
  __builtin_amdgcn_global_load_lds(
      (const __attribute__((address_space(1))) void*)g,
      (__attribute__((address_space(3))) void*)l, 16, 0, 0);
}
__device__ __forceinline__ void store16_lds(void* p, const u16 u[8]){
  u32 d0 = (u32)u[0] | ((u32)u[1]<<16);
  u32 d1 = (u32)u[2] | ((u32)u[3]<<16);
  u32 d2 = (u32)u[4] | ((u32)u[5]<<16);
  u32 d3 = (u32)u[6] | ((u32)u[7]<<16);
  int4 vv; vv.x=(int)d0; vv.y=(int)d1; vv.z=(int)d2; vv.w=(int)d3;
  *(int4*)p = vv;
}

// ---------------- prep: W1 -> W1T bf16 [128][512]; W2,b2 -> B2T bf16 [512][960]
__global__ __launch_bounds__(256) void prep_kernel(
    const float* __restrict__ W1, const float* __restrict__ W2,
    const float* __restrict__ b2, u16* __restrict__ W1T, u16* __restrict__ B2T)
{
  int e = blockIdx.x*256 + threadIdx.x;
  if (e < ND*NH){
    int k = e >> 7, h = e & (NH-1);
    W1T[h*ND + k] = f2bf(W1[e]);
  } else if (e < ND*NH + NH*NKW*NF){
    int c = e - ND*NH;
    int h = c / (NKW*NF);
    int col = c - h*(NKW*NF);
    int k = col >> 9, n = col & (NF-1);
    B2T[(size_t)n*KP + k*NH + h] = f2bf(W2[c]);
  } else if (e < ND*NH + NH*NKW*NF + NF*64){
    int c = e - (ND*NH + NH*NKW*NF);
    int n = c >> 6, j = c & 63;
    B2T[(size_t)n*KP + 896 + j] = (j < NKW) ? f2bf(b2[j*NF + n]) : (u16)0;
  }
}

// ---------------- rowsum: rs[t] = sum_d x[t,d]
__global__ __launch_bounds__(256) void rowsum_kernel(
    const float* __restrict__ x, float* __restrict__ rs)
{
  int t = blockIdx.x*4 + (threadIdx.x>>6);
  int l = threadIdx.x & 63;
  const float4* p = (const float4*)(x + (size_t)t*ND + l*8);
  float4 a = p[0], b = p[1];
  float s = (a.x+a.y)+(a.z+a.w)+((b.x+b.y)+(b.z+b.w));
  #pragma unroll
  for (int m=1;m<64;m<<=1) s += __shfl_xor(s, m);
  if (l==0) rs[t] = s;
}

// ---------------- gemm1: h = relu(x @ W1 + b1), bf16 out [16384][128]
// BM=64, BN=128, BK=64, 4 waves (wave tile 64x32)
__global__ __launch_bounds__(256) void gemm1_kernel(
    const float* __restrict__ x, const u16* __restrict__ W1T,
    const float* __restrict__ b1, u16* __restrict__ hout)
{
  __shared__ __align__(16) u16 At[64*64];    // 8KB, swizzled rows of 128B
  __shared__ __align__(16) u16 Bt[128*64];   // 16KB
  const int tid = threadIdx.x, w = tid>>6, l = tid&63;
  const int m_base = blockIdx.x*64;
  f32x4 acc[4][2] = {};
  for (int kc=0; kc<8; ++kc){
    if (kc) __syncthreads();
    // stage A: x f32 -> bf16, swizzled
    #pragma unroll
    for (int it=0; it<2; ++it){
      int c = tid + it*256;
      int row = c>>3, slot = c&7;
      const float4* px = (const float4*)(x + (size_t)(m_base+row)*ND + kc*64 + slot*8);
      float4 a = px[0], b = px[1];
      u16 u[8] = {f2bf(a.x),f2bf(a.y),f2bf(a.z),f2bf(a.w),
                  f2bf(b.x),f2bf(b.y),f2bf(b.z),f2bf(b.w)};
      int byte = row*128 + ((slot*16) ^ ((row&7)<<4));
      store16_lds((char*)At + byte, u);
    }
    // stage B: async, source pre-swizzled
    #pragma unroll
    for (int i=0;i<4;++i){
      int rowbase = i*32 + w*8;
      char* ldsbase = (char*)Bt + rowbase*128;
      int n = rowbase + (l>>3);
      const char* g = (const char*)W1T + (size_t)n*1024 + kc*128
                      + (((l&7)*16) ^ (((l>>3)&7)<<4));
      gload_lds16(g, ldsbase);
    }
    asm volatile("s_waitcnt vmcnt(0)" ::: "memory");
    __syncthreads();
    #pragma unroll
    for (int kk=0; kk<2; ++kk){
      bf16x8 af[4], bfr[2];
      #pragma unroll
      for (int mi=0;mi<4;++mi){
        int row = mi*16 + (l&15);
        int byte = row*128 + (((kk*64)+((l>>4)*16)) ^ ((row&7)<<4));
        af[mi] = *(const bf16x8*)((const char*)At + byte);
      }
      #pragma unroll
      for (int ni=0;ni<2;++ni){
        int row = w*32 + ni*16 + (l&15);
        int byte = row*128 + (((kk*64)+((l>>4)*16)) ^ ((row&7)<<4));
        bfr[ni] = *(const bf16x8*)((const char*)Bt + byte);
      }
      #pragma unroll
      for (int mi=0;mi<4;++mi)
        #pragma unroll
        for (int ni=0;ni<2;++ni)
          acc[mi][ni] = __builtin_amdgcn_mfma_f32_16x16x32_bf16(af[mi], bfr[ni], acc[mi][ni], 0,0,0);
    }
  }
  #pragma unroll
  for (int ni=0;ni<2;++ni){
    int n = w*32 + ni*16 + (l&15);
    float bias = b1[n];
    #pragma unroll
    for (int mi=0;mi<4;++mi){
      #pragma unroll
      for (int r=0;r<4;++r){
        int m = mi*16 + (l>>4)*4 + r;
        float v = fmaxf(acc[mi][ni][r] + bias, 0.f);
        hout[(size_t)(m_base+m)*NH + n] = f2bf(v);
      }
    }
  }
}

// ---------------- gemm2: conv_out = A'(s*h) @ B2T  + residual + LN + relu
// M=16384, N=512, K'=960. BM=64, BN=512, BK=64, 8 waves (wave tile 64x64)
__global__ __launch_bounds__(512) void gemm2_kernel(
    const float* __restrict__ x, const u16* __restrict__ hbuf,
    const u16* __restrict__ B2T, const float* __restrict__ rs,
    const float* __restrict__ gamma, const float* __restrict__ beta,
    float* __restrict__ out)
{
  __shared__ __align__(16) u16 At[64*64];       // 8KB
  __shared__ __align__(16) u16 Bt[512*64];      // 64KB
  __shared__ float s_lds[64][8];
  __shared__ float g_lds[512], be_lds[512];
  __shared__ float red_s[64][8], red_q[64][8];
  __shared__ float mu_lds[64], rstd_lds[64];

  const int tid = threadIdx.x, w = tid>>6, l = tid&63;
  const int m_base = blockIdx.x*64;

  g_lds[tid] = gamma[tid];
  be_lds[tid] = beta[tid];
  {
    int row = tid>>3, k = tid&7;
    float v = 0.f;
    if (k < NKW){
      int tg = m_base + row;
      int ti = tg & (NT-1);
      int idx = ti + k - 3;
      if (idx >= 0 && idx < NT) v = rs[(tg & ~(NT-1)) + idx];
    }
    s_lds[row][k] = v;
  }

  f32x4 acc[4][4] = {};
  for (int kc=0; kc<15; ++kc){
    __syncthreads();
    // stage A': s*h (bf16), swizzled; chunk 14 = raw s values (bias rows)
    {
      int row = tid>>3, slot = tid&7;
      u16 u[8];
      if (kc < 14){
        float sv = s_lds[row][kc>>1];
        u16x8 hv = *(const u16x8*)(hbuf + (size_t)(m_base+row)*NH + (kc&1)*64 + slot*8);
        #pragma unroll
        for (int j=0;j<8;++j) u[j] = f2bf(bf2f(hv[j])*sv);
      } else {
        #pragma unroll
        for (int j=0;j<8;++j){
          int e2 = slot*8+j;
          float v = (e2<NKW)? s_lds[row][e2] : 0.f;
          u[j] = f2bf(v);
        }
      }
      int byte = row*128 + ((slot*16) ^ ((row&7)<<4));
      store16_lds((char*)At + byte, u);
    }
    // stage B: async global_load_lds, source pre-swizzled
    #pragma unroll
    for (int i=0;i<8;++i){
      int rowbase = i*64 + w*8;
      char* ldsbase = (char*)Bt + rowbase*128;
      int n = rowbase + (l>>3);
      const char* g = (const char*)B2T + (size_t)n*(KP*2) + kc*128
                      + (((l&7)*16) ^ (((l>>3)&7)<<4));
      gload_lds16(g, ldsbase);
    }
    asm volatile("s_waitcnt vmcnt(0)" ::: "memory");
    __syncthreads();
    #pragma unroll
    for (int kk=0; kk<2; ++kk){
      bf16x8 af[4], bfr[4];
      #pragma unroll
      for (int mi=0;mi<4;++mi){
        int row = mi*16 + (l&15);
        int byte = row*128 + (((kk*64)+((l>>4)*16)) ^ ((row&7)<<4));
        af[mi] = *(const bf16x8*)((const char*)At + byte);
      }
      #pragma unroll
      for (int ni=0;ni<4;++ni){
        int row = w*64 + ni*16 + (l&15);
        int byte = row*128 + (((kk*64)+((l>>4)*16)) ^ ((row&7)<<4));
        bfr[ni] = *(const bf16x8*)((const char*)Bt + byte);
      }
      #pragma unroll
      for (int mi=0;mi<4;++mi)
        #pragma unroll
        for (int ni=0;ni<4;++ni)
          acc[mi][ni] = __builtin_amdgcn_mfma_f32_16x16x32_bf16(af[mi], bfr[ni], acc[mi][ni], 0,0,0);
    }
  }
  // epilogue: +x residual, LN stats across 8 waves, normalize, relu
  #pragma unroll
  for (int mi=0;mi<4;++mi){
    #pragma unroll
    for (int r=0;r<4;++r){
      int m = mi*16 + (l>>4)*4 + r;
      int tg = m_base + m;
      float ps=0.f, pq=0.f;
      #pragma unroll
      for (int ni=0;ni<4;++ni){
        int n = w*64 + ni*16 + (l&15);
        float v = acc[mi][ni][r] + x[(size_t)tg*ND + n];
        acc[mi][ni][r] = v;
        ps += v; pq += v*v;
      }
      #pragma unroll
      for (int msk=1; msk<16; msk<<=1){ ps += __shfl_xor(ps,msk); pq += __shfl_xor(pq,msk); }
      if ((l&15)==0){ red_s[m][w]=ps; red_q[m][w]=pq; }
    }
  }
  __syncthreads();
  if (tid < 64){
    float ssum=0.f, sq=0.f;
    #pragma unroll
    for (int ww=0; ww<8; ++ww){ ssum += red_s[tid][ww]; sq += red_q[tid][ww]; }
    float mu = ssum * (1.0f/ND);
    float var = sq*(1.0f/ND) - mu*mu;
    mu_lds[tid] = mu;
    rstd_lds[tid] = rsqrtf(var + 1e-3f);
  }
  __syncthreads();
  #pragma unroll
  for (int mi=0;mi<4;++mi){
    #pragma unroll
    for (int r=0;r<4;++r){
      int m = mi*16 + (l>>4)*4 + r;
      int tg = m_base + m;
      float mu = mu_lds[m], rstd = rstd_lds[m];
      #pragma unroll
      for (int ni=0;ni<4;++ni){
        int n = w*64 + ni*16 + (l&15);
        float v = (acc[mi][ni][r]-mu)*rstd*g_lds[n] + be_lds[n];
        out[(size_t)tg*ND + n] = fmaxf(v, 0.f);
      }
    }
  }
}

extern "C" void kernel_launch(void* const* d_in, const int* in_sizes, int n_in,
                              void* d_out, int out_size, void* d_ws, size_t ws_size,
                              hipStream_t stream)
{
  (void)in_sizes; (void)n_in; (void)out_size; (void)ws_size;
  const float* x     = (const float*)d_in[0];
  const float* W1    = (const float*)d_in[1];
  const float* b1    = (const float*)d_in[2];
  const float* W2    = (const float*)d_in[3];
  const float* b2    = (const float*)d_in[4];
  const float* gamma = (const float*)d_in[5];
  const float* beta  = (const float*)d_in[6];
  float* out = (float*)d_out;

  char* ws = (char*)d_ws;
  u16*   W1T  = (u16*)(ws);                              // 131072 B
  u16*   B2T  = (u16*)(ws + 131072);                     // 983040 B
  float* rs   = (float*)(ws + 131072 + 983040);          // 65536 B
  u16*   hbuf = (u16*)(ws + 131072 + 983040 + 65536);    // 4 MB

  prep_kernel<<<2176, 256, 0, stream>>>(W1, W2, b2, W1T, B2T);
  rowsum_kernel<<<NTOK/4, 256, 0, stream>>>(x, rs);
  gemm1_kernel<<<NTOK/64, 256, 0, stream>>>(x, W1T, b1, hbuf);
  gemm2_kernel<<<NTOK/64, 512, 0, stream>>>(x, hbuf, B2T, rs, gamma, beta, out);
}

// Round 2
// 142.082 us; speedup vs baseline: 1.0432x; 1.0432x over previous
//
#include <hip/hip_runtime.h>

#define NT 2048
#define ND 512
#define NH 128
#define NKW 7
#define KP 960

typedef float f32x4 __attribute__((ext_vector_type(4)));
typedef __bf16 bf16x8 __attribute__((ext_vector_type(8)));
typedef unsigned short u16;
typedef unsigned int u32;
typedef u16 u16x8 __attribute__((ext_vector_type(8)));

__device__ __forceinline__ u16 f2bf(float f){
  u32 u = __builtin_bit_cast(u32, f);
  return (u16)((u + 0x7fffu + ((u>>16)&1u)) >> 16);
}
__device__ __forceinline__ float bf2f(u16 s){
  u32 u = ((u32)s)<<16;
  return __builtin_bit_cast(float, u);
}
__device__ __forceinline__ void store16_lds(void* p, const u16 u[8]){
  u32 d0 = (u32)u[0] | ((u32)u[1]<<16);
  u32 d1 = (u32)u[2] | ((u32)u[3]<<16);
  u32 d2 = (u32)u[4] | ((u32)u[5]<<16);
  u32 d3 = (u32)u[6] | ((u32)u[7]<<16);
  int4 vv; vv.x=(int)d0; vv.y=(int)d1; vv.z=(int)d2; vv.w=(int)d3;
  *(int4*)p = vv;
}

// ---------------- prep: coalesced transposes via LDS tile
// blocks 0..15: W1 [512][128] -> W1T [128][512]
// blocks 16..127: W2 [128][3584] -> B2T [512][960] (col = k*128+h)
// blocks 128..135: bias rows B2T[n][896+j] = (j<7)? b2[j*512+n] : 0
__global__ __launch_bounds__(256) void prep_kernel(
    const float* __restrict__ W1, const float* __restrict__ W2,
    const float* __restrict__ b2, u16* __restrict__ W1T, u16* __restrict__ B2T)
{
  __shared__ float T[64][65];
  const int b = blockIdx.x, tid = threadIdx.x;
  if (b < 16){
    const int d0 = (b>>1)*64, h0 = (b&1)*64;
    #pragma unroll
    for (int r=0;r<16;++r){
      int idx=r*256+tid; int dl=idx>>6, hl=idx&63;
      T[dl][hl] = W1[(size_t)(d0+dl)*NH + h0+hl];
    }
    __syncthreads();
    #pragma unroll
    for (int r=0;r<16;++r){
      int idx=r*256+tid; int hl=idx>>6, dl=idx&63;
      W1T[(size_t)(h0+hl)*ND + d0+dl] = f2bf(T[dl][hl]);
    }
  } else if (b < 128){
    const int bb = b-16;
    const int h0 = (bb&1)*64, c0 = (bb>>1)*64;
    #pragma unroll
    for (int r=0;r<16;++r){
      int idx=r*256+tid; int hl=idx>>6, cl=idx&63;
      T[hl][cl] = W2[(size_t)(h0+hl)*(NKW*ND) + c0+cl];
    }
    __syncthreads();
    #pragma unroll
    for (int r=0;r<16;++r){
      int idx=r*256+tid; int cl=idx>>6, hl=idx&63;
      int c = c0+cl; int n = c & (ND-1), k = c >> 9;
      B2T[(size_t)n*KP + k*NH + h0+hl] = f2bf(T[hl][cl]);
    }
  } else {
    const int bb = b-128;
    #pragma unroll
    for (int r=0;r<16;++r){
      int idx = bb*4096 + r*256 + tid;
      int n = idx>>6, j = idx&63;
      B2T[(size_t)n*KP + 896 + j] = (j<NKW)? f2bf(b2[(size_t)j*ND+n]) : (u16)0;
    }
  }
}

// B-fragment direct loads (L2-resident operand)
__device__ __forceinline__ void loadB2(const char* B2T, int kc, int w, int l,
                                       bf16x8 (*bf)[4]){
  #pragma unroll
  for (int kk=0;kk<2;++kk)
    #pragma unroll
    for (int ni=0;ni<4;++ni){
      int rowB = w*64 + ni*16 + (l&15);
      bf[kk][ni] = *(const bf16x8*)(B2T + (size_t)rowB*(KP*2) + kc*128 + kk*64 + (l>>4)*16);
    }
}
__device__ __forceinline__ void loadB1(const char* W1T, int kc, int w, int l,
                                       bf16x8 (*bf)[2]){
  #pragma unroll
  for (int kk=0;kk<2;++kk)
    #pragma unroll
    for (int ni=0;ni<2;++ni){
      int rowB = w*32 + ni*16 + (l&15);
      bf[kk][ni] = *(const bf16x8*)(W1T + (size_t)rowB*(ND*2) + kc*128 + kk*64 + (l>>4)*16);
    }
}

// ---------------- gemm1: h = relu(x @ W1 + b1)  + fused rowsum
// BM=32, N=128, K=512 (8 chunks), 4 waves, grid 512 (2 blocks/CU)
__global__ __launch_bounds__(256,2) void gemm1_kernel(
    const float* __restrict__ x, const u16* __restrict__ W1T,
    const float* __restrict__ b1, u16* __restrict__ hout, float* __restrict__ rs)
{
  __shared__ __align__(16) u16 At[2][32*64];   // 4KB x2
  const int tid = threadIdx.x, w = tid>>6, l = tid&63;
  const int m_base = blockIdx.x*32;
  const int row = tid>>3, slot = tid&7;
  const float* xrow = x + (size_t)(m_base+row)*ND + slot*8;
  float rsum = 0.f;
  f32x4 acc[2][2] = {};
  bf16x8 bufA[2][2], bufB[2][2];

  auto stageA = [&](u16* dst, const float4& p0, const float4& p1){
    rsum += (p0.x+p0.y)+(p0.z+p0.w)+((p1.x+p1.y)+(p1.z+p1.w));
    u16 u[8] = {f2bf(p0.x),f2bf(p0.y),f2bf(p0.z),f2bf(p0.w),
                f2bf(p1.x),f2bf(p1.y),f2bf(p1.z),f2bf(p1.w)};
    int byte = row*128 + ((slot*16) ^ ((row&7)<<4));
    store16_lds((char*)dst + byte, u);
  };

  float4 c0 = *(const float4*)(xrow);
  float4 c1 = *(const float4*)(xrow+4);
  loadB1((const char*)W1T, 0, w, l, bufA);
  stageA(At[0], c0, c1);
  __syncthreads();

  #pragma unroll
  for (int kc=0;kc<8;++kc){
    bf16x8 (*bc)[2] = (kc&1)? bufB : bufA;
    bf16x8 (*bn)[2] = (kc&1)? bufA : bufB;
    float4 n0, n1;
    if (kc<7){
      n0 = *(const float4*)(xrow + (kc+1)*64);
      n1 = *(const float4*)(xrow + (kc+1)*64 + 4);
      loadB1((const char*)W1T, kc+1, w, l, bn);
    }
    const char* curA = (const char*)At[kc&1];
    #pragma unroll
    for (int kk=0;kk<2;++kk){
      bf16x8 af[2];
      #pragma unroll
      for (int mi=0;mi<2;++mi){
        int r2 = mi*16 + (l&15);
        int byte = r2*128 + (((kk*64)+((l>>4)*16)) ^ ((r2&7)<<4));
        af[mi] = *(const bf16x8*)(curA + byte);
      }
      #pragma unroll
      for (int mi=0;mi<2;++mi)
        #pragma unroll
        for (int ni=0;ni<2;++ni)
          acc[mi][ni] = __builtin_amdgcn_mfma_f32_16x16x32_bf16(af[mi], bc[kk][ni], acc[mi][ni],0,0,0);
    }
    if (kc<7){
      stageA(At[(kc&1)^1], n0, n1);
      __syncthreads();
    }
  }
  // rowsum: reduce over the 8 slot-lanes sharing this row, write once
  rsum += __shfl_xor(rsum,1);
  rsum += __shfl_xor(rsum,2);
  rsum += __shfl_xor(rsum,4);
  if ((tid&7)==0) rs[m_base+row] = rsum;
  // epilogue: bias + relu -> bf16 hbuf
  #pragma unroll
  for (int ni=0;ni<2;++ni){
    int n = w*32 + ni*16 + (l&15);
    float bias = b1[n];
    #pragma unroll
    for (int mi=0;mi<2;++mi){
      #pragma unroll
      for (int r=0;r<4;++r){
        int m = mi*16 + (l>>4)*4 + r;
        float v = fmaxf(acc[mi][ni][r] + bias, 0.f);
        hout[(size_t)(m_base+m)*NH + n] = f2bf(v);
      }
    }
  }
}

// ---------------- gemm2: conv = A'(s*h) @ B2T + residual + LN + relu
// BM=64, BN=512, K'=960 (15 chunks of 64), 8 waves, grid 256
__global__ __launch_bounds__(512,2) void gemm2_kernel(
    const float* __restrict__ x, const u16* __restrict__ hbuf,
    const u16* __restrict__ B2T, const float* __restrict__ rs,
    const float* __restrict__ gamma, const float* __restrict__ beta,
    float* __restrict__ out)
{
  __shared__ __align__(16) u16 At[2][64*64];     // 8KB x2
  __shared__ float s_lds[64][8];
  __shared__ float red_s[64][8], red_q[64][8];
  __shared__ float mu_lds[64], rstd_lds[64];

  const int tid = threadIdx.x, w = tid>>6, l = tid&63;
  const int m_base = blockIdx.x*64;
  const int row = tid>>3, slot = tid&7;

  // s values for this tile (window row-sums, zero-padded at sequence edges)
  {
    int rr = tid>>3, k = tid&7;
    float v = 0.f;
    if (k < NKW){
      int tg = m_base + rr;
      int ti = tg & (NT-1);
      int idx = ti + k - 3;
      if (idx >= 0 && idx < NT) v = rs[(tg & ~(NT-1)) + idx];
    }
    s_lds[rr][k] = v;
  }
  // hoisted h-halves for this thread's staging row (reused every chunk)
  u16x8 hv_e = *(const u16x8*)(hbuf + (size_t)(m_base+row)*NH + slot*8);
  u16x8 hv_o = *(const u16x8*)(hbuf + (size_t)(m_base+row)*NH + 64 + slot*8);

  bf16x8 bufA[2][4], bufB[2][4];
  loadB2((const char*)B2T, 0, w, l, bufA);

  auto stageA = [&](u16* dst, int kc2){
    u16 u[8];
    if (kc2 < 14){
      float sv = s_lds[row][kc2>>1];
      u16x8 hv = (kc2&1)? hv_o : hv_e;
      #pragma unroll
      for (int j=0;j<8;++j) u[j] = f2bf(bf2f(hv[j])*sv);
    } else {
      #pragma unroll
      for (int j=0;j<8;++j){
        int e2 = slot*8+j;
        u[j] = (e2<NKW)? f2bf(s_lds[row][e2]) : (u16)0;
      }
    }
    int byte = row*128 + ((slot*16) ^ ((row&7)<<4));
    store16_lds((char*)dst + byte, u);
  };

  __syncthreads();            // s_lds visible
  stageA(At[0], 0);
  __syncthreads();            // At[0] visible

  f32x4 acc[4][4] = {};
  #pragma unroll
  for (int kc=0;kc<15;++kc){
    bf16x8 (*bc)[4] = (kc&1)? bufB : bufA;
    bf16x8 (*bn)[4] = (kc&1)? bufA : bufB;
    if (kc<14) loadB2((const char*)B2T, kc+1, w, l, bn);
    const char* curA = (const char*)At[kc&1];
    #pragma unroll
    for (int kk=0;kk<2;++kk){
      bf16x8 af[4];
      #pragma unroll
      for (int mi=0;mi<4;++mi){
        int r2 = mi*16 + (l&15);
        int byte = r2*128 + (((kk*64)+((l>>4)*16)) ^ ((r2&7)<<4));
        af[mi] = *(const bf16x8*)(curA + byte);
      }
      #pragma unroll
      for (int mi=0;mi<4;++mi)
        #pragma unroll
        for (int ni=0;ni<4;++ni)
          acc[mi][ni] = __builtin_amdgcn_mfma_f32_16x16x32_bf16(af[mi], bc[kk][ni], acc[mi][ni],0,0,0);
    }
    if (kc<14){
      stageA(At[(kc&1)^1], kc+1);
      __syncthreads();
    }
  }

  // epilogue: +x residual, LN across the full 512-row, relu
  #pragma unroll
  for (int mi=0;mi<4;++mi){
    #pragma unroll
    for (int r=0;r<4;++r){
      int m = mi*16 + (l>>4)*4 + r;
      int tg = m_base + m;
      float ps=0.f, pq=0.f;
      #pragma unroll
      for (int ni=0;ni<4;++ni){
        int n = w*64 + ni*16 + (l&15);
        float v = acc[mi][ni][r] + x[(size_t)tg*ND + n];
        acc[mi][ni][r] = v;
        ps += v; pq += v*v;
      }
      #pragma unroll
      for (int msk=1; msk<16; msk<<=1){ ps += __shfl_xor(ps,msk); pq += __shfl_xor(pq,msk); }
      if ((l&15)==0){ red_s[m][w]=ps; red_q[m][w]=pq; }
    }
  }
  __syncthreads();
  if (tid < 64){
    float ssum=0.f, sq=0.f;
    #pragma unroll
    for (int ww=0; ww<8; ++ww){ ssum += red_s[tid][ww]; sq += red_q[tid][ww]; }
    float mu = ssum * (1.0f/ND);
    float var = sq*(1.0f/ND) - mu*mu;
    mu_lds[tid] = mu;
    rstd_lds[tid] = rsqrtf(var + 1e-3f);
  }
  __syncthreads();
  float gv[4], bv[4];
  #pragma unroll
  for (int ni=0;ni<4;++ni){
    int n = w*64 + ni*16 + (l&15);
    gv[ni] = gamma[n]; bv[ni] = beta[n];
  }
  #pragma unroll
  for (int mi=0;mi<4;++mi){
    #pragma unroll
    for (int r=0;r<4;++r){
      int m = mi*16 + (l>>4)*4 + r;
      int tg = m_base + m;
      float mu = mu_lds[m], rstd = rstd_lds[m];
      #pragma unroll
      for (int ni=0;ni<4;++ni){
        int n = w*64 + ni*16 + (l&15);
        float v = (acc[mi][ni][r]-mu)*rstd*gv[ni] + bv[ni];
        out[(size_t)tg*ND + n] = fmaxf(v, 0.f);
      }
    }
  }
}

extern "C" void kernel_launch(void* const* d_in, const int* in_sizes, int n_in,
                              void* d_out, int out_size, void* d_ws, size_t ws_size,
                              hipStream_t stream)
{
  (void)in_sizes; (void)n_in; (void)out_size; (void)ws_size;
  const float* x     = (const float*)d_in[0];
  const float* W1    = (const float*)d_in[1];
  const float* b1    = (const float*)d_in[2];
  const float* W2    = (const float*)d_in[3];
  const float* b2    = (const float*)d_in[4];
  const float* gamma = (const float*)d_in[5];
  const float* beta  = (const float*)d_in[6];
  float* out = (float*)d_out;

  char* ws = (char*)d_ws;
  u16*   W1T  = (u16*)(ws);                              // 131072 B
  u16*   B2T  = (u16*)(ws + 131072);                     // 983040 B
  float* rs   = (float*)(ws + 131072 + 983040);          // 65536 B
  u16*   hbuf = (u16*)(ws + 131072 + 983040 + 65536);    // 4 MB

  prep_kernel<<<136, 256, 0, stream>>>(W1, W2, b2, W1T, B2T);
  gemm1_kernel<<<512, 256, 0, stream>>>(x, W1T, b1, hbuf, rs);
  gemm2_kernel<<<256, 512, 0, stream>>>(x, hbuf, B2T, rs, gamma, beta, out);
}